// Round 15
// baseline (183.251 us; speedup 1.0000x reference)
//
#include <hip/hip_runtime.h>
#include <hip/hip_bf16.h>
#include <hip/hip_fp16.h>

typedef __attribute__((ext_vector_type(8))) short bf16x8;
typedef __attribute__((ext_vector_type(8))) unsigned short u16x8;
typedef __attribute__((ext_vector_type(4))) float f32x4;

__device__ __forceinline__ unsigned short f2bf(float f) {
    unsigned u = __float_as_uint(f);
    u += 0x7fffu + ((u >> 16) & 1u);
    return (unsigned short)(u >> 16);
}
__device__ __forceinline__ float bf2f(unsigned short b) {
    return __uint_as_float(((unsigned)b) << 16);
}

#define GLOAD_LDS16(g, l)                                                           \
    __builtin_amdgcn_global_load_lds(                                               \
        (const __attribute__((address_space(1))) void*)(g),                         \
        (__attribute__((address_space(3))) void*)(l), 16, 0, 0)

// =====================================================================
// 256x256 deep-pipelined GEMM, BK=64, 8 waves (2Mx4N), counted vmcnt.
// (round-2/5 schedule — unchanged from the round-14 PASSING build)
// C = A * B^T : A[M][K] bf16, B[N][K] bf16 row-major.
// OMODE 0: C bf16 (plain store).
// OMODE 2: QK epilogue — C = bf16(exp(acc/32)) causal-masked at store;
//          tiles with bn > bm never read by causal PV -> store skipped;
//          per-row UNMASKED sums (bf16-rounded) atomicAdd'd into Zb.
// OMODE 3: V epilogue — write ONLY the transposed projection
//          Vt[b][d][s] (S=2048) via LDS bounce. Separate instantiation
//          so OMODE 0/2 keep their clean codegen (rule #19 fix).
// =====================================================================
#define TBM 256
#define TBN 256
#define TBK 64

template <int OMODE>
__global__ __launch_bounds__(512, 2) void gemm256(
    const unsigned short* __restrict__ A, const unsigned short* __restrict__ B,
    void* __restrict__ Cv, float* __restrict__ Zb,
    unsigned short* __restrict__ VtOut, int M, int N, int K,
    long long sA, long long sB, long long sC) {
    constexpr int LDSN = (OMODE == 3) ? 256 * 264 : 2 * 4 * 128 * 64;
    __shared__ unsigned short ldsraw[LDSN];
    typedef unsigned short LdsBuf[4][128 * 64];
    LdsBuf* lds = (LdsBuf*)ldsraw;

    const int bz = blockIdx.z;
    A += (size_t)bz * (size_t)sA;
    B += (size_t)bz * (size_t)sB;

    const int bm = blockIdx.x, bn = blockIdx.y;
    const int tid = threadIdx.x;
    const int wid = tid >> 6, lane = tid & 63;
    const int wr = wid >> 2, wc = wid & 3;       // 2 x 4 wave grid
    const int frow = lane & 15, kgrp = lane >> 4;
    const int nt = K / TBK;

    const unsigned short* Abase = A + (size_t)(bm * TBM) * K;
    const unsigned short* Bbase = B + (size_t)(bn * TBN) * K;

    // stage one 128x64 half-tile: 2 x gload_lds(16B) per thread.
    auto STAGE_H = [&](const unsigned short* gtb, int kt, unsigned short* dsthalf) {
#pragma unroll
        for (int ld = 0; ld < 2; ++ld) {
            const int c = tid + ld * 512;
            const int row = c >> 3, c8 = c & 7;
            GLOAD_LDS16(gtb + (size_t)row * K + kt * TBK + ((c8 ^ (row & 7)) << 3),
                        (char*)dsthalf + ld * 8192 + wid * 1024);
        }
    };

    f32x4 acc[8][4];
#pragma unroll
    for (int i = 0; i < 8; ++i)
#pragma unroll
        for (int j = 0; j < 4; ++j) acc[i][j] = (f32x4){0.f, 0.f, 0.f, 0.f};

    // prologue: tile 0 -> buf 0  (8 loads in flight)
    STAGE_H(Bbase, 0, &lds[0][2][0]);
    STAGE_H(Bbase + 128 * (size_t)K, 0, &lds[0][3][0]);
    STAGE_H(Abase, 0, &lds[0][0][0]);
    STAGE_H(Abase + 128 * (size_t)K, 0, &lds[0][1][0]);

    for (int t = 0; t < nt; ++t) {
        const int buf = t & 1, bufN = buf ^ 1;
        const unsigned short* Ah = &lds[buf][wr][0];
        const unsigned short* Bh = &lds[buf][2 + (wc >> 1)][0];

        // ---- phase 1: stage next B halves, counted wait, barrier ----
        if (t + 1 < nt) {
            STAGE_H(Bbase, t + 1, &lds[bufN][2][0]);
            STAGE_H(Bbase + 128 * (size_t)K, t + 1, &lds[bufN][3][0]);
            asm volatile("s_waitcnt vmcnt(4)" ::: "memory");
        } else {
            asm volatile("s_waitcnt vmcnt(0)" ::: "memory");
        }
        __builtin_amdgcn_s_barrier();

        // B fragments for the whole K-tile (held in regs across phases)
        bf16x8 bfrag[4][2];
#pragma unroll
        for (int n = 0; n < 4; ++n) {
            const int rB = (wc & 1) * 64 + n * 16 + frow;
            const int sw = (rB & 7) << 3;
#pragma unroll
            for (int kk = 0; kk < 2; ++kk)
                bfrag[n][kk] =
                    *(const bf16x8*)&Bh[rB * 64 + ((((kk << 2) + kgrp) << 3) ^ sw)];
        }
        {
            bf16x8 afrag[2][2];
#pragma unroll
            for (int m2 = 0; m2 < 2; ++m2) {
                const int rA = m2 * 16 + frow;
                const int sw = (rA & 7) << 3;
#pragma unroll
                for (int kk = 0; kk < 2; ++kk)
                    afrag[m2][kk] =
                        *(const bf16x8*)&Ah[rA * 64 + ((((kk << 2) + kgrp) << 3) ^ sw)];
            }
            __builtin_amdgcn_s_setprio(1);
#pragma unroll
            for (int m2 = 0; m2 < 2; ++m2)
#pragma unroll
                for (int n = 0; n < 4; ++n)
#pragma unroll
                    for (int kk = 0; kk < 2; ++kk)
                        acc[m2][n] = __builtin_amdgcn_mfma_f32_16x16x32_bf16(
                            afrag[m2][kk], bfrag[n][kk], acc[m2][n], 0, 0, 0);
            __builtin_amdgcn_s_setprio(0);
        }

        // ---- phases 2..4: stage next A halves, compute bands 1..3 ----
#pragma unroll
        for (int q = 1; q < 4; ++q) {
            if (q == 1 && t + 1 < nt) STAGE_H(Abase, t + 1, &lds[bufN][0][0]);
            if (q == 2 && t + 1 < nt)
                STAGE_H(Abase + 128 * (size_t)K, t + 1, &lds[bufN][1][0]);
            bf16x8 afrag[2][2];
#pragma unroll
            for (int m2 = 0; m2 < 2; ++m2) {
                const int rA = q * 32 + m2 * 16 + frow;
                const int sw = (rA & 7) << 3;
#pragma unroll
                for (int kk = 0; kk < 2; ++kk)
                    afrag[m2][kk] =
                        *(const bf16x8*)&Ah[rA * 64 + ((((kk << 2) + kgrp) << 3) ^ sw)];
            }
            __builtin_amdgcn_s_setprio(1);
#pragma unroll
            for (int m2 = 0; m2 < 2; ++m2)
#pragma unroll
                for (int n = 0; n < 4; ++n)
#pragma unroll
                    for (int kk = 0; kk < 2; ++kk)
                        acc[q * 2 + m2][n] = __builtin_amdgcn_mfma_f32_16x16x32_bf16(
                            afrag[m2][kk], bfrag[n][kk], acc[q * 2 + m2][n], 0, 0, 0);
            __builtin_amdgcn_s_setprio(0);
        }
    }

    // epilogue: rows wr*128 + mi*16 + kgrp*4 + rr ; cols wc*64 + n*16 + frow
    const size_t row0 = (size_t)bm * TBM + wr * 128 + kgrp * 4;
    const int col0 = bn * TBN + wc * 64 + frow;
    if (OMODE == 0) {
        unsigned short* Cp = (unsigned short*)Cv + (size_t)bz * (size_t)sC;
#pragma unroll
        for (int mi = 0; mi < 8; ++mi)
#pragma unroll
            for (int rr = 0; rr < 4; ++rr) {
                unsigned short* op = Cp + (row0 + mi * 16 + rr) * N + col0;
#pragma unroll
                for (int n = 0; n < 4; ++n) op[n * 16] = f2bf(acc[mi][n][rr]);
            }
    } else if (OMODE == 3) {
        // ---- fused V transpose: LDS bounce, write ONLY Vt[b][d][s] ----
        __syncthreads();  // all staging reads done; LDS reusable
        unsigned short (*T)[264] = (unsigned short (*)[264])ldsraw;
        const int rloc = wr * 128 + kgrp * 4;
#pragma unroll
        for (int mi = 0; mi < 8; ++mi)
#pragma unroll
            for (int rr = 0; rr < 4; ++rr)
#pragma unroll
                for (int n = 0; n < 4; ++n)
                    T[wc * 64 + n * 16 + frow][rloc + mi * 16 + rr] =
                        f2bf(acc[mi][n][rr]);
        __syncthreads();
        const int c = tid >> 1, rh = (tid & 1) * 128;
        const int b = bm >> 3;            // S=2048, TBM=256
        const int srow0 = (bm & 7) * 256;
        unsigned short* vp = VtOut +
            ((size_t)b * N + (size_t)(bn * TBN + c)) * 2048 + srow0 + rh;
#pragma unroll
        for (int k = 0; k < 16; ++k)
            *(u16x8*)(vp + k * 8) = *(const u16x8*)&T[c][rh + k * 8];
    } else {
        unsigned short* Cp = (unsigned short*)Cv + (size_t)bz * (size_t)sC;
        const bool doStore = (bn <= bm);  // PV never reads tiles with bn > bm
        float rs[8][4];
#pragma unroll
        for (int mi = 0; mi < 8; ++mi)
#pragma unroll
            for (int rr = 0; rr < 4; ++rr) {
                const int rowg = (int)(row0 + mi * 16 + rr);
                unsigned short* op = Cp + (size_t)rowg * N + col0;
                float zsum = 0.f;
#pragma unroll
                for (int n = 0; n < 4; ++n) {
                    float e = __expf(acc[mi][n][rr] * 0.03125f);
                    unsigned short pb = f2bf(e);
                    zsum += bf2f(pb);  // Z from the rounded value (consistency)
                    if (doStore)
                        op[n * 16] = (col0 + n * 16 <= rowg) ? pb : (unsigned short)0;
                }
                rs[mi][rr] = zsum;
            }
        // reduce over the 16 frow lanes (distinct cols of this wave)
#pragma unroll
        for (int mi = 0; mi < 8; ++mi)
#pragma unroll
            for (int rr = 0; rr < 4; ++rr) {
                float v = rs[mi][rr];
                v += __shfl_xor(v, 1);
                v += __shfl_xor(v, 2);
                v += __shfl_xor(v, 4);
                v += __shfl_xor(v, 8);
                rs[mi][rr] = v;
            }
        if (frow == 0) {
            float* Zr = Zb + (size_t)bz * M + row0;
#pragma unroll
            for (int mi = 0; mi < 8; ++mi)
#pragma unroll
                for (int rr = 0; rr < 4; ++rr)
                    atomicAdd(&Zr[mi * 16 + rr], rs[mi][rr]);
        }
    }
}

// =====================================================================
// PV GEMM, BM=128 x BN=32 x BK=64, 4 waves (2Mx2N, 16 cols/wave).
// A = P_unnorm bf16 [S][S] (causal K-skip), B = Vt bf16 [D][S].
// C f32 scaled by 1/Z[row].
// Round-15: BN 64->32. Round-14 (BK=64) confirmed PV latency-bound;
// with 2 blocks/CU the per-iter barrier+drain is still half-exposed.
// BN=32 -> LDS 40 KiB -> grid (8,32,4) = 1024 uniform blocks = 4
// INDEPENDENT blocks/CU whose drains interleave (2x the overlap).
// Extra A-panel refetch absorbed by L3 (P 32MB + Vt 16MB resident).
// Two-half balanced bm = {NBM-1-bx, bx} (uniform 34 tiles/block, no
// co-residency assumptions) and m97-style syncthreads loop unchanged.
// Staging/fragment swizzle formulas = gemm256's proven 0-conflict map.
// =====================================================================
#define BM 128
#define BN 32
#define BK 64

__global__ __launch_bounds__(256) void gemm_pv(
    const unsigned short* __restrict__ A, const unsigned short* __restrict__ B,
    float* __restrict__ C, const float* __restrict__ Z, int M, int N, int K,
    long long sA, long long sB, long long sC) {
    __shared__ unsigned short As[2][BM * BK];  // 32 KiB
    __shared__ unsigned short Bs[2][BN * BK];  // 8 KiB

    const int bz = blockIdx.z;
    A += (size_t)bz * (size_t)sA;
    B += (size_t)bz * (size_t)sB;

    const int bn = blockIdx.y;
    const int tid = threadIdx.x;
    const int wid = tid >> 6;
    const int lane = tid & 63;
    const int wr = wid >> 1, wc = wid & 1;   // 2M x 2N waves, 16 cols each
    const int frow = lane & 15;
    const int kgrp = lane >> 4;
    const int NBM = gridDim.x * 2;

    const unsigned short* Bbase = B + (size_t)(bn * BN) * K;
    float* Cp = C + (size_t)bz * (size_t)sC;
    const float* Zp = Z + (size_t)bz * M;

    for (int half = 0; half < 2; ++half) {
        const int bm = half ? blockIdx.x : (NBM - 1 - blockIdx.x);
        const unsigned short* Abase = A + (size_t)(bm * BM) * K;

        int nt = K / BK;
        {
            int lim = (bm + 1) * (BM / BK);  // causal K-tile skip
            if (lim < nt) nt = lim;
        }

        // gemm256's proven map: chunk c -> row=c>>3, c8=c&7; source chunk
        // (c8 ^ (row&7)); LDS dest linear = c*16 B. A: 1024 chunks
        // (4/thread); B: 256 chunks (1/thread).
        auto STAGE = [&](int kt, int buf) {
            const unsigned short* Ag = Abase + kt * BK;
            const unsigned short* Bg = Bbase + kt * BK;
#pragma unroll
            for (int ld = 0; ld < 4; ++ld) {
                const int c = tid + ld * 256;
                const int row = c >> 3, c8 = c & 7;
                GLOAD_LDS16(Ag + (size_t)row * K + ((c8 ^ (row & 7)) << 3),
                            (char*)&As[buf][0] + ld * 4096 + wid * 1024 + lane * 16);
            }
            {
                const int c = tid;
                const int row = c >> 3, c8 = c & 7;
                GLOAD_LDS16(Bg + (size_t)row * K + ((c8 ^ (row & 7)) << 3),
                            (char*)&Bs[buf][0] + wid * 1024 + lane * 16);
            }
        };

        f32x4 acc[4];
#pragma unroll
        for (int mi = 0; mi < 4; ++mi) acc[mi] = (f32x4){0.f, 0.f, 0.f, 0.f};

        STAGE(0, 0);
        __syncthreads();

        for (int kt = 0; kt < nt; ++kt) {
            const int buf = kt & 1;
            if (kt + 1 < nt) STAGE(kt + 1, buf ^ 1);
            bf16x8 af[4][2], bfr[2];
#pragma unroll
            for (int mi = 0; mi < 4; ++mi) {
                const int row = wr * 64 + mi * 16 + frow;
                const int sw = (row & 7) << 3;
#pragma unroll
                for (int kk = 0; kk < 2; ++kk)
                    af[mi][kk] = *(const bf16x8*)
                        &As[buf][row * BK + ((((kk << 2) + kgrp) << 3) ^ sw)];
            }
            {
                const int col = wc * 16 + frow;
                const int sw = (col & 7) << 3;
#pragma unroll
                for (int kk = 0; kk < 2; ++kk)
                    bfr[kk] = *(const bf16x8*)
                        &Bs[buf][col * BK + ((((kk << 2) + kgrp) << 3) ^ sw)];
            }
#pragma unroll
            for (int mi = 0; mi < 4; ++mi)
#pragma unroll
                for (int kk = 0; kk < 2; ++kk)
                    acc[mi] = __builtin_amdgcn_mfma_f32_16x16x32_bf16(
                        af[mi][kk], bfr[kk], acc[mi], 0, 0, 0);
            __syncthreads();
        }

        const size_t row0 = (size_t)bm * BM + wr * 64 + kgrp * 4;
        const int col0 = bn * BN + wc * 16 + frow;
#pragma unroll
        for (int mi = 0; mi < 4; ++mi)
#pragma unroll
            for (int r = 0; r < 4; ++r) {
                const float ri = 1.0f / Zp[row0 + mi * 16 + r];
                Cp[(row0 + mi * 16 + r) * N + col0] = acc[mi][r] * ri;
            }
        // loop's trailing __syncthreads() fenced all LDS reads; epilogue is
        // global-only, so next half's STAGE is safe.
    }
}

// x f32 -> bf16, plus Zd zeroing folded in (one fewer launch)
__global__ __launch_bounds__(256) void cvt_f32_bf16(
    const float* __restrict__ in, unsigned short* __restrict__ out, int n,
    float* __restrict__ z, int nz) {
    int idx = blockIdx.x * blockDim.x + threadIdx.x;
    if (idx < nz) z[idx] = 0.f;
    int stride = gridDim.x * blockDim.x;
    for (int i = idx * 4; i < n; i += stride * 4) {
        float4 v = *(const float4*)(in + i);
        ushort4 o;
        o.x = f2bf(v.x); o.y = f2bf(v.y); o.z = f2bf(v.z); o.w = f2bf(v.w);
        *(ushort4*)(out + i) = o;
    }
}

// out[n][k] = (bf16) in[k][n];  in: [Kd][Nd] f32
__global__ __launch_bounds__(256) void transpose_cvt_w(
    const float* __restrict__ in, unsigned short* __restrict__ out, int Kd, int Nd) {
    __shared__ float t[32][33];
    const int tr = blockIdx.y * 32, tc = blockIdx.x * 32;
    const int r = threadIdx.x >> 3, c4 = (threadIdx.x & 7) * 4;
    float4 v = *(const float4*)&in[(size_t)(tr + r) * Nd + tc + c4];
    t[r][c4 + 0] = v.x; t[r][c4 + 1] = v.y; t[r][c4 + 2] = v.z; t[r][c4 + 3] = v.w;
    __syncthreads();
    ushort4 o;
    o.x = f2bf(t[c4 + 0][r]); o.y = f2bf(t[c4 + 1][r]);
    o.z = f2bf(t[c4 + 2][r]); o.w = f2bf(t[c4 + 3][r]);
    *(ushort4*)&out[(size_t)(tc + r) * Kd + tr + c4] = o;
}

extern "C" void kernel_launch(void* const* d_in, const int* in_sizes, int n_in,
                              void* d_out, int out_size, void* d_ws, size_t ws_size,
                              hipStream_t stream) {
    const int B = 4, S = 2048, D = 1024;
    const size_t M = (size_t)B * S;  // 8192

    const float* x = (const float*)d_in[0];
    float* out = (float*)d_out;

    unsigned short* xb = (unsigned short*)d_ws;        // M*D
    unsigned short* Wt = xb + M * D;                   // 3*D*D
    unsigned short* Qb = Wt + 3 * (size_t)D * D;       // M*D
    unsigned short* Kb = Qb + M * D;                   // M*D
    unsigned short* Vb = Kb + M * D;                   // M*D (unused)
    unsigned short* Vt = Vb + M * D;                   // M*D
    unsigned short* Sc = Vt + M * D;                   // B*S*S (bf16 P_unnorm)
    float* Zd = (float*)(Sc + (size_t)B * S * S);      // B*S f32
    const size_t need =
        (size_t)(M * D * 5 + 3 * (size_t)D * D + (size_t)B * S * S) * 2 +
        (size_t)B * S * 4;
    if (ws_size < need) return;

    cvt_f32_bf16<<<2048, 256, 0, stream>>>(x, xb, (int)(M * D), Zd, B * S);
    dim3 tg(D / 32, D / 32, 1);
    transpose_cvt_w<<<tg, 256, 0, stream>>>((const float*)d_in[1], Wt + 0 * (size_t)D * D, D, D);
    transpose_cvt_w<<<tg, 256, 0, stream>>>((const float*)d_in[2], Wt + 1 * (size_t)D * D, D, D);
    transpose_cvt_w<<<tg, 256, 0, stream>>>((const float*)d_in[3], Wt + 2 * (size_t)D * D, D, D);

    // Q,K projections: z=2 over {Wq,Wk}; same A (strideA=0). 256 blocks.
    gemm256<0><<<dim3(M / TBM, D / TBN, 2), 512, 0, stream>>>(
        xb, Wt, (void*)Qb, nullptr, nullptr, (int)M, D, D, 0LL,
        (long long)D * D, (long long)(M * D));

    // V projection: separate instantiation writes Vt[b][d][s] directly.
    gemm256<3><<<dim3(M / TBM, D / TBN, 1), 512, 0, stream>>>(
        xb, Wt + 2 * (size_t)D * D, nullptr, nullptr, Vt, (int)M, D, D, 0LL,
        0LL, 0LL);

    // P_unnorm = exp(Q K^T / 32) bf16 (masked; dead tiles unstored),
    // Z = unmasked row sums (atomic)
    gemm256<2><<<dim3(S / TBM, S / TBN, B), 512, 0, stream>>>(
        Qb, Kb, (void*)Sc, Zd, nullptr, S, S, D, (long long)S * D,
        (long long)S * D, (long long)S * S);

    // context = (P_unnorm @ V) / Z, causal skip, balanced two-half blocks,
    // BN=32 -> 1024 uniform blocks = 4 independent blocks/CU
    gemm_pv<<<dim3(S / BM / 2, D / BN, B), 256, 0, stream>>>(
        Sc, Vt, out, Zd, S, D, S, (long long)S * S, (long long)D * S,
        (long long)S * D);
}

// Round 16
// 160.375 us; speedup vs baseline: 1.1426x; 1.1426x over previous
//
#include <hip/hip_runtime.h>
#include <hip/hip_bf16.h>
#include <hip/hip_fp16.h>

typedef __attribute__((ext_vector_type(8))) short bf16x8;
typedef __attribute__((ext_vector_type(8))) unsigned short u16x8;
typedef __attribute__((ext_vector_type(4))) float f32x4;

__device__ __forceinline__ unsigned short f2bf(float f) {
    unsigned u = __float_as_uint(f);
    u += 0x7fffu + ((u >> 16) & 1u);
    return (unsigned short)(u >> 16);
}
__device__ __forceinline__ float bf2f(unsigned short b) {
    return __uint_as_float(((unsigned)b) << 16);
}

#define GLOAD_LDS16(g, l)                                                           \
    __builtin_amdgcn_global_load_lds(                                               \
        (const __attribute__((address_space(1))) void*)(g),                         \
        (__attribute__((address_space(3))) void*)(l), 16, 0, 0)

// =====================================================================
// 256x256 deep-pipelined GEMM, BK=64, 8 waves (2Mx4N), counted vmcnt.
// (round-2/5 schedule — unchanged from the round-14 PASSING champion)
// C = A * B^T : A[M][K] bf16, B[N][K] bf16 row-major.
// OMODE 0: C bf16 (plain store).
// OMODE 2: QK epilogue — C = bf16(exp(acc/32)) causal-masked at store;
//          tiles with bn > bm never read by causal PV -> store skipped;
//          per-row UNMASKED sums (bf16-rounded) atomicAdd'd into Zb.
// OMODE 3: V epilogue — write ONLY the transposed projection
//          Vt[b][d][s] (S=2048) via LDS bounce. Separate instantiation
//          so OMODE 0/2 keep their clean codegen (rule #19 fix).
// =====================================================================
#define TBM 256
#define TBN 256
#define TBK 64

template <int OMODE>
__global__ __launch_bounds__(512, 2) void gemm256(
    const unsigned short* __restrict__ A, const unsigned short* __restrict__ B,
    void* __restrict__ Cv, float* __restrict__ Zb,
    unsigned short* __restrict__ VtOut, int M, int N, int K,
    long long sA, long long sB, long long sC) {
    constexpr int LDSN = (OMODE == 3) ? 256 * 264 : 2 * 4 * 128 * 64;
    __shared__ unsigned short ldsraw[LDSN];
    typedef unsigned short LdsBuf[4][128 * 64];
    LdsBuf* lds = (LdsBuf*)ldsraw;

    const int bz = blockIdx.z;
    A += (size_t)bz * (size_t)sA;
    B += (size_t)bz * (size_t)sB;

    const int bm = blockIdx.x, bn = blockIdx.y;
    const int tid = threadIdx.x;
    const int wid = tid >> 6, lane = tid & 63;
    const int wr = wid >> 2, wc = wid & 3;       // 2 x 4 wave grid
    const int frow = lane & 15, kgrp = lane >> 4;
    const int nt = K / TBK;

    const unsigned short* Abase = A + (size_t)(bm * TBM) * K;
    const unsigned short* Bbase = B + (size_t)(bn * TBN) * K;

    // stage one 128x64 half-tile: 2 x gload_lds(16B) per thread.
    auto STAGE_H = [&](const unsigned short* gtb, int kt, unsigned short* dsthalf) {
#pragma unroll
        for (int ld = 0; ld < 2; ++ld) {
            const int c = tid + ld * 512;
            const int row = c >> 3, c8 = c & 7;
            GLOAD_LDS16(gtb + (size_t)row * K + kt * TBK + ((c8 ^ (row & 7)) << 3),
                        (char*)dsthalf + ld * 8192 + wid * 1024);
        }
    };

    f32x4 acc[8][4];
#pragma unroll
    for (int i = 0; i < 8; ++i)
#pragma unroll
        for (int j = 0; j < 4; ++j) acc[i][j] = (f32x4){0.f, 0.f, 0.f, 0.f};

    // prologue: tile 0 -> buf 0  (8 loads in flight)
    STAGE_H(Bbase, 0, &lds[0][2][0]);
    STAGE_H(Bbase + 128 * (size_t)K, 0, &lds[0][3][0]);
    STAGE_H(Abase, 0, &lds[0][0][0]);
    STAGE_H(Abase + 128 * (size_t)K, 0, &lds[0][1][0]);

    for (int t = 0; t < nt; ++t) {
        const int buf = t & 1, bufN = buf ^ 1;
        const unsigned short* Ah = &lds[buf][wr][0];
        const unsigned short* Bh = &lds[buf][2 + (wc >> 1)][0];

        // ---- phase 1: stage next B halves, counted wait, barrier ----
        if (t + 1 < nt) {
            STAGE_H(Bbase, t + 1, &lds[bufN][2][0]);
            STAGE_H(Bbase + 128 * (size_t)K, t + 1, &lds[bufN][3][0]);
            asm volatile("s_waitcnt vmcnt(4)" ::: "memory");
        } else {
            asm volatile("s_waitcnt vmcnt(0)" ::: "memory");
        }
        __builtin_amdgcn_s_barrier();

        // B fragments for the whole K-tile (held in regs across phases)
        bf16x8 bfrag[4][2];
#pragma unroll
        for (int n = 0; n < 4; ++n) {
            const int rB = (wc & 1) * 64 + n * 16 + frow;
            const int sw = (rB & 7) << 3;
#pragma unroll
            for (int kk = 0; kk < 2; ++kk)
                bfrag[n][kk] =
                    *(const bf16x8*)&Bh[rB * 64 + ((((kk << 2) + kgrp) << 3) ^ sw)];
        }
        {
            bf16x8 afrag[2][2];
#pragma unroll
            for (int m2 = 0; m2 < 2; ++m2) {
                const int rA = m2 * 16 + frow;
                const int sw = (rA & 7) << 3;
#pragma unroll
                for (int kk = 0; kk < 2; ++kk)
                    afrag[m2][kk] =
                        *(const bf16x8*)&Ah[rA * 64 + ((((kk << 2) + kgrp) << 3) ^ sw)];
            }
            __builtin_amdgcn_s_setprio(1);
#pragma unroll
            for (int m2 = 0; m2 < 2; ++m2)
#pragma unroll
                for (int n = 0; n < 4; ++n)
#pragma unroll
                    for (int kk = 0; kk < 2; ++kk)
                        acc[m2][n] = __builtin_amdgcn_mfma_f32_16x16x32_bf16(
                            afrag[m2][kk], bfrag[n][kk], acc[m2][n], 0, 0, 0);
            __builtin_amdgcn_s_setprio(0);
        }

        // ---- phases 2..4: stage next A halves, compute bands 1..3 ----
#pragma unroll
        for (int q = 1; q < 4; ++q) {
            if (q == 1 && t + 1 < nt) STAGE_H(Abase, t + 1, &lds[bufN][0][0]);
            if (q == 2 && t + 1 < nt)
                STAGE_H(Abase + 128 * (size_t)K, t + 1, &lds[bufN][1][0]);
            bf16x8 afrag[2][2];
#pragma unroll
            for (int m2 = 0; m2 < 2; ++m2) {
                const int rA = q * 32 + m2 * 16 + frow;
                const int sw = (rA & 7) << 3;
#pragma unroll
                for (int kk = 0; kk < 2; ++kk)
                    afrag[m2][kk] =
                        *(const bf16x8*)&Ah[rA * 64 + ((((kk << 2) + kgrp) << 3) ^ sw)];
            }
            __builtin_amdgcn_s_setprio(1);
#pragma unroll
            for (int m2 = 0; m2 < 2; ++m2)
#pragma unroll
                for (int n = 0; n < 4; ++n)
#pragma unroll
                    for (int kk = 0; kk < 2; ++kk)
                        acc[q * 2 + m2][n] = __builtin_amdgcn_mfma_f32_16x16x32_bf16(
                            afrag[m2][kk], bfrag[n][kk], acc[q * 2 + m2][n], 0, 0, 0);
            __builtin_amdgcn_s_setprio(0);
        }
    }

    // epilogue: rows wr*128 + mi*16 + kgrp*4 + rr ; cols wc*64 + n*16 + frow
    const size_t row0 = (size_t)bm * TBM + wr * 128 + kgrp * 4;
    const int col0 = bn * TBN + wc * 64 + frow;
    if (OMODE == 0) {
        unsigned short* Cp = (unsigned short*)Cv + (size_t)bz * (size_t)sC;
#pragma unroll
        for (int mi = 0; mi < 8; ++mi)
#pragma unroll
            for (int rr = 0; rr < 4; ++rr) {
                unsigned short* op = Cp + (row0 + mi * 16 + rr) * N + col0;
#pragma unroll
                for (int n = 0; n < 4; ++n) op[n * 16] = f2bf(acc[mi][n][rr]);
            }
    } else if (OMODE == 3) {
        // ---- fused V transpose: LDS bounce, write ONLY Vt[b][d][s] ----
        __syncthreads();  // all staging reads done; LDS reusable
        unsigned short (*T)[264] = (unsigned short (*)[264])ldsraw;
        const int rloc = wr * 128 + kgrp * 4;
#pragma unroll
        for (int mi = 0; mi < 8; ++mi)
#pragma unroll
            for (int rr = 0; rr < 4; ++rr)
#pragma unroll
                for (int n = 0; n < 4; ++n)
                    T[wc * 64 + n * 16 + frow][rloc + mi * 16 + rr] =
                        f2bf(acc[mi][n][rr]);
        __syncthreads();
        const int c = tid >> 1, rh = (tid & 1) * 128;
        const int b = bm >> 3;            // S=2048, TBM=256
        const int srow0 = (bm & 7) * 256;
        unsigned short* vp = VtOut +
            ((size_t)b * N + (size_t)(bn * TBN + c)) * 2048 + srow0 + rh;
#pragma unroll
        for (int k = 0; k < 16; ++k)
            *(u16x8*)(vp + k * 8) = *(const u16x8*)&T[c][rh + k * 8];
    } else {
        unsigned short* Cp = (unsigned short*)Cv + (size_t)bz * (size_t)sC;
        const bool doStore = (bn <= bm);  // PV never reads tiles with bn > bm
        float rs[8][4];
#pragma unroll
        for (int mi = 0; mi < 8; ++mi)
#pragma unroll
            for (int rr = 0; rr < 4; ++rr) {
                const int rowg = (int)(row0 + mi * 16 + rr);
                unsigned short* op = Cp + (size_t)rowg * N + col0;
                float zsum = 0.f;
#pragma unroll
                for (int n = 0; n < 4; ++n) {
                    float e = __expf(acc[mi][n][rr] * 0.03125f);
                    unsigned short pb = f2bf(e);
                    zsum += bf2f(pb);  // Z from the rounded value (consistency)
                    if (doStore)
                        op[n * 16] = (col0 + n * 16 <= rowg) ? pb : (unsigned short)0;
                }
                rs[mi][rr] = zsum;
            }
        // reduce over the 16 frow lanes (distinct cols of this wave)
#pragma unroll
        for (int mi = 0; mi < 8; ++mi)
#pragma unroll
            for (int rr = 0; rr < 4; ++rr) {
                float v = rs[mi][rr];
                v += __shfl_xor(v, 1);
                v += __shfl_xor(v, 2);
                v += __shfl_xor(v, 4);
                v += __shfl_xor(v, 8);
                rs[mi][rr] = v;
            }
        if (frow == 0) {
            float* Zr = Zb + (size_t)bz * M + row0;
#pragma unroll
            for (int mi = 0; mi < 8; ++mi)
#pragma unroll
                for (int rr = 0; rr < 4; ++rr)
                    atomicAdd(&Zr[mi * 16 + rr], rs[mi][rr]);
        }
    }
}

// =====================================================================
// PV GEMM, BM=128 x BN=64 x BK=64, 4 waves (2Mx2N) — round-14 champion
// config (163.5 us total). Round-15's BN=32 regressed (halved per-iter
// MFMA at fixed per-iter latency): REVERTED.
// A = P_unnorm bf16 [S][S] (causal K-skip), B = Vt bf16 [D][S].
// C f32 scaled by 1/Z[row]. Two-half balanced bm = {NBM-1-bx, bx}
// (uniform 34 K-tiles/block, no co-residency assumptions).
// Staging/fragment swizzle = gemm256's proven 0-conflict map.
// LDS 48 KiB -> 2 blocks/CU at 512 blocks (balance + TLP).
// =====================================================================
#define BM 128
#define BN 64
#define BK 64

__global__ __launch_bounds__(256) void gemm_pv(
    const unsigned short* __restrict__ A, const unsigned short* __restrict__ B,
    float* __restrict__ C, const float* __restrict__ Z, int M, int N, int K,
    long long sA, long long sB, long long sC) {
    __shared__ unsigned short As[2][BM * BK];  // 32 KiB
    __shared__ unsigned short Bs[2][BN * BK];  // 16 KiB

    const int bz = blockIdx.z;
    A += (size_t)bz * (size_t)sA;
    B += (size_t)bz * (size_t)sB;

    const int bn = blockIdx.y;
    const int tid = threadIdx.x;
    const int wid = tid >> 6;
    const int lane = tid & 63;
    const int wr = wid >> 1, wc = wid & 1;   // 2M x 2N waves
    const int frow = lane & 15;
    const int kgrp = lane >> 4;
    const int NBM = gridDim.x * 2;

    const unsigned short* Bbase = B + (size_t)(bn * BN) * K;
    float* Cp = C + (size_t)bz * (size_t)sC;
    const float* Zp = Z + (size_t)bz * M;

    for (int half = 0; half < 2; ++half) {
        const int bm = half ? blockIdx.x : (NBM - 1 - blockIdx.x);
        const unsigned short* Abase = A + (size_t)(bm * BM) * K;

        int nt = K / BK;
        {
            int lim = (bm + 1) * (BM / BK);  // causal K-tile skip
            if (lim < nt) nt = lim;
        }

        // gemm256's proven map: chunk c -> row=c>>3, c8=c&7; source chunk
        // (c8 ^ (row&7)); LDS dest linear = c*16 B. A: 1024 chunks
        // (4/thread); B: 512 chunks (2/thread).
        auto STAGE = [&](int kt, int buf) {
            const unsigned short* Ag = Abase + kt * BK;
            const unsigned short* Bg = Bbase + kt * BK;
#pragma unroll
            for (int ld = 0; ld < 4; ++ld) {
                const int c = tid + ld * 256;
                const int row = c >> 3, c8 = c & 7;
                GLOAD_LDS16(Ag + (size_t)row * K + ((c8 ^ (row & 7)) << 3),
                            (char*)&As[buf][0] + ld * 4096 + wid * 1024 + lane * 16);
            }
#pragma unroll
            for (int ld = 0; ld < 2; ++ld) {
                const int c = tid + ld * 256;
                const int row = c >> 3, c8 = c & 7;
                GLOAD_LDS16(Bg + (size_t)row * K + ((c8 ^ (row & 7)) << 3),
                            (char*)&Bs[buf][0] + ld * 4096 + wid * 1024 + lane * 16);
            }
        };

        f32x4 acc[4][2];
#pragma unroll
        for (int mi = 0; mi < 4; ++mi)
#pragma unroll
            for (int ni = 0; ni < 2; ++ni)
                acc[mi][ni] = (f32x4){0.f, 0.f, 0.f, 0.f};

        STAGE(0, 0);
        __syncthreads();

        for (int kt = 0; kt < nt; ++kt) {
            const int buf = kt & 1;
            if (kt + 1 < nt) STAGE(kt + 1, buf ^ 1);
            bf16x8 af[4][2], bfr[2][2];
#pragma unroll
            for (int mi = 0; mi < 4; ++mi) {
                const int row = wr * 64 + mi * 16 + frow;
                const int sw = (row & 7) << 3;
#pragma unroll
                for (int kk = 0; kk < 2; ++kk)
                    af[mi][kk] = *(const bf16x8*)
                        &As[buf][row * BK + ((((kk << 2) + kgrp) << 3) ^ sw)];
            }
#pragma unroll
            for (int ni = 0; ni < 2; ++ni) {
                const int col = wc * 32 + ni * 16 + frow;
                const int sw = (col & 7) << 3;
#pragma unroll
                for (int kk = 0; kk < 2; ++kk)
                    bfr[ni][kk] = *(const bf16x8*)
                        &Bs[buf][col * BK + ((((kk << 2) + kgrp) << 3) ^ sw)];
            }
#pragma unroll
            for (int mi = 0; mi < 4; ++mi)
#pragma unroll
                for (int ni = 0; ni < 2; ++ni)
#pragma unroll
                    for (int kk = 0; kk < 2; ++kk)
                        acc[mi][ni] = __builtin_amdgcn_mfma_f32_16x16x32_bf16(
                            af[mi][kk], bfr[ni][kk], acc[mi][ni], 0, 0, 0);
            __syncthreads();
        }

        const size_t row0 = (size_t)bm * BM + wr * 64 + kgrp * 4;
        const int col0 = bn * BN + wc * 32 + frow;
#pragma unroll
        for (int mi = 0; mi < 4; ++mi)
#pragma unroll
            for (int r = 0; r < 4; ++r) {
                const float ri = 1.0f / Zp[row0 + mi * 16 + r];
                float* op = Cp + (row0 + mi * 16 + r) * N + col0;
#pragma unroll
                for (int ni = 0; ni < 2; ++ni) op[ni * 16] = acc[mi][ni][r] * ri;
            }
        // loop's trailing __syncthreads() fenced all LDS reads; epilogue is
        // global-only, so next half's STAGE is safe.
    }
}

// x f32 -> bf16, plus Zd zeroing folded in (one fewer launch)
__global__ __launch_bounds__(256) void cvt_f32_bf16(
    const float* __restrict__ in, unsigned short* __restrict__ out, int n,
    float* __restrict__ z, int nz) {
    int idx = blockIdx.x * blockDim.x + threadIdx.x;
    if (idx < nz) z[idx] = 0.f;
    int stride = gridDim.x * blockDim.x;
    for (int i = idx * 4; i < n; i += stride * 4) {
        float4 v = *(const float4*)(in + i);
        ushort4 o;
        o.x = f2bf(v.x); o.y = f2bf(v.y); o.z = f2bf(v.z); o.w = f2bf(v.w);
        *(ushort4*)(out + i) = o;
    }
}

// out[n][k] = (bf16) in[k][n];  in: [Kd][Nd] f32.  z=3 batched over the
// three weight matrices (one launch instead of three — launch-overhead fusion).
__global__ __launch_bounds__(256) void transpose_cvt_w3(
    const float* __restrict__ w0, const float* __restrict__ w1,
    const float* __restrict__ w2, unsigned short* __restrict__ out,
    int Kd, int Nd) {
    __shared__ float t[32][33];
    const int bz = blockIdx.z;
    const float* in = (bz == 0) ? w0 : (bz == 1) ? w1 : w2;
    unsigned short* op = out + (size_t)bz * Kd * Nd;
    const int tr = blockIdx.y * 32, tc = blockIdx.x * 32;
    const int r = threadIdx.x >> 3, c4 = (threadIdx.x & 7) * 4;
    float4 v = *(const float4*)&in[(size_t)(tr + r) * Nd + tc + c4];
    t[r][c4 + 0] = v.x; t[r][c4 + 1] = v.y; t[r][c4 + 2] = v.z; t[r][c4 + 3] = v.w;
    __syncthreads();
    ushort4 o;
    o.x = f2bf(t[c4 + 0][r]); o.y = f2bf(t[c4 + 1][r]);
    o.z = f2bf(t[c4 + 2][r]); o.w = f2bf(t[c4 + 3][r]);
    *(ushort4*)&op[(size_t)(tc + r) * Kd + tr + c4] = o;
}

extern "C" void kernel_launch(void* const* d_in, const int* in_sizes, int n_in,
                              void* d_out, int out_size, void* d_ws, size_t ws_size,
                              hipStream_t stream) {
    const int B = 4, S = 2048, D = 1024;
    const size_t M = (size_t)B * S;  // 8192

    const float* x = (const float*)d_in[0];
    float* out = (float*)d_out;

    unsigned short* xb = (unsigned short*)d_ws;        // M*D
    unsigned short* Wt = xb + M * D;                   // 3*D*D
    unsigned short* Qb = Wt + 3 * (size_t)D * D;       // M*D
    unsigned short* Kb = Qb + M * D;                   // M*D
    unsigned short* Vb = Kb + M * D;                   // M*D (unused)
    unsigned short* Vt = Vb + M * D;                   // M*D
    unsigned short* Sc = Vt + M * D;                   // B*S*S (bf16 P_unnorm)
    float* Zd = (float*)(Sc + (size_t)B * S * S);      // B*S f32
    const size_t need =
        (size_t)(M * D * 5 + 3 * (size_t)D * D + (size_t)B * S * S) * 2 +
        (size_t)B * S * 4;
    if (ws_size < need) return;

    cvt_f32_bf16<<<2048, 256, 0, stream>>>(x, xb, (int)(M * D), Zd, B * S);
    transpose_cvt_w3<<<dim3(D / 32, D / 32, 3), 256, 0, stream>>>(
        (const float*)d_in[1], (const float*)d_in[2], (const float*)d_in[3],
        Wt, D, D);

    // Q,K projections: z=2 over {Wq,Wk}; same A (strideA=0). 256 blocks.
    gemm256<0><<<dim3(M / TBM, D / TBN, 2), 512, 0, stream>>>(
        xb, Wt, (void*)Qb, nullptr, nullptr, (int)M, D, D, 0LL,
        (long long)D * D, (long long)(M * D));

    // V projection: separate instantiation writes Vt[b][d][s] directly.
    gemm256<3><<<dim3(M / TBM, D / TBN, 1), 512, 0, stream>>>(
        xb, Wt + 2 * (size_t)D * D, nullptr, nullptr, Vt, (int)M, D, D, 0LL,
        0LL, 0LL);

    // P_unnorm = exp(Q K^T / 32) bf16 (masked; dead tiles unstored),
    // Z = unmasked row sums (atomic)
    gemm256<2><<<dim3(S / TBM, S / TBN, B), 512, 0, stream>>>(
        Qb, Kb, (void*)Sc, Zd, nullptr, S, S, D, (long long)S * D,
        (long long)S * D, (long long)S * S);

    // context = (P_unnorm @ V) / Z, causal skip, balanced two-half blocks,
    // BK=64 / BN=64 (round-14 champion config), 512 uniform blocks = 2/CU
    gemm_pv<<<dim3(S / BM / 2, D / BN, B), 256, 0, stream>>>(
        Sc, Vt, out, Zd, S, D, S, (long long)S * S, (long long)D * S,
        (long long)S * D);
}